// Round 1
// baseline (272.251 us; speedup 1.0000x reference)
//
#include <hip/hip_runtime.h>

#define NROWS 8192
#define HID   1024
#define NSAMP 8192
#define LCOLS 8193          // NSAMP + 1
#define NEG_INF_F (-1e37f)

typedef __attribute__((ext_vector_type(8))) __bf16 bf16x8;
typedef __attribute__((ext_vector_type(4))) float f32x4;
typedef __attribute__((ext_vector_type(8))) unsigned short u16x8;

__device__ __forceinline__ unsigned short f2bf(float x) {
  unsigned u = __float_as_uint(x);
  u += 0x7fffu + ((u >> 16) & 1u);       // round-to-nearest-even
  return (unsigned short)(u >> 16);
}

#define GLOAD_LDS16(g, l)                                                      \
  __builtin_amdgcn_global_load_lds(                                            \
      (const __attribute__((address_space(1))) void*)(g),                      \
      (__attribute__((address_space(3))) void*)(l), 16, 0, 0)

// ---------------- fp32 -> bf16 convert of the activations ----------------
__global__ void k_cvtA(const float* __restrict__ A, unsigned short* __restrict__ Ab,
                       int total4) {
  int i = blockIdx.x * blockDim.x + threadIdx.x;
  int stride = gridDim.x * blockDim.x;
  for (; i < total4; i += stride) {
    float4 v = ((const float4*)A)[i];
    ushort4 o;
    o.x = f2bf(v.x); o.y = f2bf(v.y); o.z = f2bf(v.z); o.w = f2bf(v.w);
    ((ushort4*)Ab)[i] = o;
  }
}

// ------------- gather sampled weight rows, convert to bf16 ---------------
__global__ void k_gatherB(const float* __restrict__ W, const int* __restrict__ sid,
                          unsigned short* __restrict__ Bb) {
  int s = blockIdx.x;                       // one block per sampled row
  int id = sid[s];
  float4 v = ((const float4*)(W + (size_t)id * HID))[threadIdx.x];
  ushort4 o;
  o.x = f2bf(v.x); o.y = f2bf(v.y); o.z = f2bf(v.z); o.w = f2bf(v.w);
  ((ushort4*)(Bb + (size_t)s * HID))[threadIdx.x] = o;
}

// ------------- true-class logits (column 0) + new_targets ----------------
__global__ void k_true(const float* __restrict__ X, const int* __restrict__ tgt,
                       const float* __restrict__ W, const float* __restrict__ bias,
                       const float* __restrict__ tfreq, float* __restrict__ out) {
  int n = blockIdx.x;
  int t = tgt[n];
  float4 a = ((const float4*)(X + (size_t)n * HID))[threadIdx.x];
  float4 w = ((const float4*)(W + (size_t)t * HID))[threadIdx.x];
  float p = a.x * w.x + a.y * w.y + a.z * w.z + a.w * w.w;
  #pragma unroll
  for (int off = 32; off > 0; off >>= 1) p += __shfl_down(p, off);
  __shared__ float red[4];
  if ((threadIdx.x & 63) == 0) red[threadIdx.x >> 6] = p;
  __syncthreads();
  if (threadIdx.x == 0) {
    float v = red[0] + red[1] + red[2] + red[3] + bias[t] - __logf(tfreq[n]);
    out[(size_t)n * LCOLS] = v;                       // logits[n, 0]
    ((int*)out)[(size_t)NROWS * LCOLS + n] = 0;       // new_targets[n] = 0
  }
}

// ---------------- 128x128 bf16 NT-GEMM with fused epilogue ----------------
// C[n, 1+s] = (sum_k A[n,k]*B[s,k]) + bias[sid[s]] - log(sfreq[s]),
// masked to -1e37 where tgt[n] == sid[s].
#define COMPUTE_STEP()                                                          \
  do {                                                                          \
    bf16x8 af_[4], bf_[4];                                                      \
    const int rl_ = l & 15, kq_ = l >> 4;                                       \
    _Pragma("unroll") for (int m = 0; m < 4; m++)                               \
        af_[m] = *(const bf16x8*)&sA[(wm * 64 + m * 16 + rl_) * 32 + kq_ * 8];  \
    _Pragma("unroll") for (int n = 0; n < 4; n++)                               \
        bf_[n] = *(const bf16x8*)&sB[(wn * 64 + n * 16 + rl_) * 32 + kq_ * 8];  \
    _Pragma("unroll") for (int m = 0; m < 4; m++)                               \
      _Pragma("unroll") for (int n = 0; n < 4; n++)                             \
          acc[m][n] = __builtin_amdgcn_mfma_f32_16x16x32_bf16(                  \
              af_[m], bf_[n], acc[m][n], 0, 0, 0);                              \
  } while (0)

__device__ __forceinline__ void pack8(unsigned short* p, float4 a, float4 b) {
  u16x8 v;
  v[0] = f2bf(a.x); v[1] = f2bf(a.y); v[2] = f2bf(a.z); v[3] = f2bf(a.w);
  v[4] = f2bf(b.x); v[5] = f2bf(b.y); v[6] = f2bf(b.z); v[7] = f2bf(b.w);
  *(u16x8*)p = v;
}

template <int USE_WS>
__global__ __launch_bounds__(256)
void k_gemm(const unsigned short* __restrict__ Ab, const unsigned short* __restrict__ Bb,
            const float* __restrict__ Af, const float* __restrict__ W,
            const int* __restrict__ tgt, const int* __restrict__ sid,
            const float* __restrict__ bias, const float* __restrict__ sfreq,
            float* __restrict__ out) {
  __shared__ unsigned short sA[128 * 32];
  __shared__ unsigned short sB[128 * 32];
  const int t = threadIdx.x;
  const int w = t >> 6, l = t & 63;
  const int m0 = blockIdx.y * 128, n0 = blockIdx.x * 128;
  const int wm = w >> 1, wn = w & 1;
  f32x4 acc[4][4] = {};
  const int srow = w * 16 + (l >> 2);     // 0..63 staged row within half-tile
  const int scol = (l & 3) * 8;           // staged k-offset

  if (USE_WS) {
    const unsigned short* ga = Ab + (size_t)(m0 + srow) * HID + scol;
    const unsigned short* gb = Bb + (size_t)(n0 + srow) * HID + scol;
    for (int kk = 0; kk < HID; kk += 32) {
      __syncthreads();
      GLOAD_LDS16(ga + kk,            sA + w * 512);
      GLOAD_LDS16(ga + 64 * HID + kk, sA + 2048 + w * 512);
      GLOAD_LDS16(gb + kk,            sB + w * 512);
      GLOAD_LDS16(gb + 64 * HID + kk, sB + 2048 + w * 512);
      __syncthreads();
      COMPUTE_STEP();
    }
  } else {
    // no-workspace fallback: reg-stage fp32, convert, ds_write
    const int id0 = sid[n0 + srow], id1 = sid[n0 + 64 + srow];
    const float* gaf0 = Af + (size_t)(m0 + srow) * HID + scol;
    const float* gaf1 = gaf0 + (size_t)64 * HID;
    const float* gbf0 = W + (size_t)id0 * HID + scol;
    const float* gbf1 = W + (size_t)id1 * HID + scol;
    for (int kk = 0; kk < HID; kk += 32) {
      float4 a0 = *(const float4*)(gaf0 + kk), a1 = *(const float4*)(gaf0 + kk + 4);
      float4 a2 = *(const float4*)(gaf1 + kk), a3 = *(const float4*)(gaf1 + kk + 4);
      float4 b0 = *(const float4*)(gbf0 + kk), b1 = *(const float4*)(gbf0 + kk + 4);
      float4 b2 = *(const float4*)(gbf1 + kk), b3 = *(const float4*)(gbf1 + kk + 4);
      __syncthreads();
      pack8(&sA[t * 8], a0, a1);
      pack8(&sA[2048 + t * 8], a2, a3);
      pack8(&sB[t * 8], b0, b1);
      pack8(&sB[2048 + t * 8], b2, b3);
      __syncthreads();
      COMPUTE_STEP();
    }
  }

  // fused epilogue
  const int rl = l & 15, rq = l >> 4;
  #pragma unroll
  for (int n = 0; n < 4; n++) {
    const int col = n0 + wn * 64 + n * 16 + rl;
    const int sv = sid[col];
    const float sbv = bias[sv] - __logf(sfreq[col]);
    #pragma unroll
    for (int m = 0; m < 4; m++) {
      const int rbase = m0 + wm * 64 + m * 16 + rq * 4;
      #pragma unroll
      for (int i = 0; i < 4; i++) {
        const int r = rbase + i;
        float c = acc[m][n][i] + sbv;
        if (tgt[r] == sv) c = NEG_INF_F;
        out[(size_t)r * LCOLS + 1 + col] = c;
      }
    }
  }
}

extern "C" void kernel_launch(void* const* d_in, const int* in_sizes, int n_in,
                              void* d_out, int out_size, void* d_ws, size_t ws_size,
                              hipStream_t stream) {
  (void)in_sizes; (void)n_in; (void)out_size;
  const float* output      = (const float*)d_in[0];
  const int*   targets     = (const int*)d_in[1];
  const int*   sample_ids  = (const int*)d_in[2];
  const float* true_freq   = (const float*)d_in[3];
  const float* sample_freq = (const float*)d_in[4];
  const float* weight      = (const float*)d_in[5];
  const float* bias        = (const float*)d_in[6];
  float* out = (float*)d_out;

  const size_t needA = (size_t)NROWS * HID * 2;
  const size_t needB = (size_t)NSAMP * HID * 2;
  const bool use_ws = ws_size >= (needA + needB);

  k_true<<<NROWS, 256, 0, stream>>>(output, targets, weight, bias, true_freq, out);

  dim3 grid(NSAMP / 128, NROWS / 128);
  if (use_ws) {
    unsigned short* Ab = (unsigned short*)d_ws;
    unsigned short* Bb = Ab + (size_t)NROWS * HID;
    k_cvtA<<<2048, 256, 0, stream>>>(output, Ab, NROWS * HID / 4);
    k_gatherB<<<NSAMP, 256, 0, stream>>>(weight, sample_ids, Bb);
    k_gemm<1><<<grid, 256, 0, stream>>>(Ab, Bb, nullptr, nullptr, targets,
                                        sample_ids, bias, sample_freq, out);
  } else {
    k_gemm<0><<<grid, 256, 0, stream>>>(nullptr, nullptr, output, weight, targets,
                                        sample_ids, bias, sample_freq, out);
  }
}

// Round 2
// 239.125 us; speedup vs baseline: 1.1385x; 1.1385x over previous
//
#include <hip/hip_runtime.h>

#define NROWS 8192
#define HID   1024
#define NSAMP 8192
#define LCOLS 8193          // NSAMP + 1
#define NEG_INF_F (-1e37f)

#define SCALE_A 127         // E8M0: 2^0
#define SCALE_B 122         // E8M0: 2^-5  (W rows pre-scaled by 32)

typedef __attribute__((ext_vector_type(4))) int   i32x4;
typedef __attribute__((ext_vector_type(8))) int   i32x8;
typedef __attribute__((ext_vector_type(4))) float f32x4;
typedef __attribute__((ext_vector_type(8))) __bf16 bf16x8;
typedef __attribute__((ext_vector_type(8))) unsigned short u16x8;

__device__ __forceinline__ unsigned short f2bf(float x) {
  unsigned u = __float_as_uint(x);
  u += 0x7fffu + ((u >> 16) & 1u);
  return (unsigned short)(u >> 16);
}

#define GLOAD_LDS16(g, l)                                                      \
  __builtin_amdgcn_global_load_lds(                                            \
      (const __attribute__((address_space(1))) void*)(g),                      \
      (__attribute__((address_space(3))) void*)(l), 16, 0, 0)

// ===================== fp8 tiled-workspace layout =====================
// ws offset of element (row = G*16 + rl, k = kk*128 + kq*32 + h*16 + j):
//   off = (G*8 + kk)*2048 + h*1024 + rl*64 + kq*16 + j
// This makes (a) global_load_lds staging fully linear/coalesced and
// (b) each ds_read_b128 (addr = gg*2048 + h*1024 + rl*64 + kq*16 over
//     lanes rl=0..15, kq=0..3) exactly tile a contiguous 1 KiB region
//     -> all 32 banks balanced, zero conflicts.
// The induced k-permutation is identical for A and B, so dot products
// are unchanged (uniform per-matrix scales).

__device__ __forceinline__ int pk4(float a, float b, float c, float d) {
  int r = __builtin_amdgcn_cvt_pk_fp8_f32(a, b, 0, 0);
  r = __builtin_amdgcn_cvt_pk_fp8_f32(c, d, r, 1);
  return r;
}

// one thread per 16 output bytes; total 8 MB / 16 = 524288 threads
__global__ void k_cvtA(const float* __restrict__ A, unsigned char* __restrict__ Ab) {
  const int t = blockIdx.x * blockDim.x + threadIdx.x;
  const int kq = t & 3, rl = (t >> 2) & 15, h = (t >> 6) & 1;
  const int kk = (t >> 7) & 7, G = t >> 10;
  const int row = G * 16 + rl;
  const int k0 = kk * 128 + kq * 32 + h * 16;
  const float4* s = (const float4*)(A + (size_t)row * HID + k0);
  float4 f0 = s[0], f1 = s[1], f2 = s[2], f3 = s[3];
  int4 o;
  o.x = pk4(f0.x, f0.y, f0.z, f0.w);
  o.y = pk4(f1.x, f1.y, f1.z, f1.w);
  o.z = pk4(f2.x, f2.y, f2.z, f2.w);
  o.w = pk4(f3.x, f3.y, f3.z, f3.w);
  ((int4*)Ab)[t] = o;
}

__global__ void k_gatherB(const float* __restrict__ W, const int* __restrict__ sid,
                          unsigned char* __restrict__ Bb) {
  const int t = blockIdx.x * blockDim.x + threadIdx.x;
  const int kq = t & 3, rl = (t >> 2) & 15, h = (t >> 6) & 1;
  const int kk = (t >> 7) & 7, G = t >> 10;
  const int srow = G * 16 + rl;
  const int id = sid[srow];
  const int k0 = kk * 128 + kq * 32 + h * 16;
  const float4* s = (const float4*)(W + (size_t)id * HID + k0);
  float4 f0 = s[0], f1 = s[1], f2 = s[2], f3 = s[3];
  const float m = 32.0f;   // descaled in-HW by SCALE_B = 2^-5
  int4 o;
  o.x = pk4(f0.x * m, f0.y * m, f0.z * m, f0.w * m);
  o.y = pk4(f1.x * m, f1.y * m, f1.z * m, f1.w * m);
  o.z = pk4(f2.x * m, f2.y * m, f2.z * m, f2.w * m);
  o.w = pk4(f3.x * m, f3.y * m, f3.z * m, f3.w * m);
  ((int4*)Bb)[t] = o;
}

// ------------- true-class logits (column 0) + new_targets ----------------
// one wave per row (64 lanes x float4 = 1024 elements)
__global__ void k_true(const float* __restrict__ X, const int* __restrict__ tgt,
                       const float* __restrict__ W, const float* __restrict__ bias,
                       const float* __restrict__ tfreq, float* __restrict__ out) {
  const int n = blockIdx.x * 4 + (threadIdx.x >> 6);
  const int l = threadIdx.x & 63;
  const int tg = tgt[n];
  float4 a = ((const float4*)(X + (size_t)n * HID))[l];
  float4 wv = ((const float4*)(W + (size_t)tg * HID))[l];
  float p = a.x * wv.x + a.y * wv.y + a.z * wv.z + a.w * wv.w;
  #pragma unroll
  for (int off = 32; off > 0; off >>= 1) p += __shfl_down(p, off);
  if (l == 0) {
    out[(size_t)n * LCOLS] = p + bias[tg] - __logf(tfreq[n]);
    ((int*)out)[(size_t)NROWS * LCOLS + n] = 0;
  }
}

// ---------------- 128x128 MX-fp8 NT-GEMM with fused epilogue ----------------
__global__ __launch_bounds__(256)
void k_gemm8(const unsigned char* __restrict__ Ab, const unsigned char* __restrict__ Bb,
             const int* __restrict__ tgt, const int* __restrict__ sid,
             const float* __restrict__ bias, const float* __restrict__ sfreq,
             float* __restrict__ out) {
  __shared__ unsigned char sA[16384];
  __shared__ unsigned char sB[16384];
  const int t = threadIdx.x, w = t >> 6, l = t & 63;
  int bid = blockIdx.y * 64 + blockIdx.x;
  bid = (bid & 7) * 512 + (bid >> 3);            // XCD swizzle (4096 % 8 == 0)
  const int m0 = (bid >> 6) * 128, n0 = (bid & 63) * 128;
  const int wm = w >> 1, wn = w & 1;
  const int rl = l & 15, kq = l >> 4;
  f32x4 acc[4][4] = {};

  // staging: issue i covers gg = 2i + (w>>1), h = w&1; 1 KiB per wave-issue
  const unsigned char* gA = Ab + (size_t)m0 * 1024 + (size_t)(w >> 1) * 16384 +
                            (w & 1) * 1024 + l * 16;
  const unsigned char* gB = Bb + (size_t)n0 * 1024 + (size_t)(w >> 1) * 16384 +
                            (w & 1) * 1024 + l * 16;

  for (int kk = 0; kk < 8; ++kk) {
    __syncthreads();
    #pragma unroll
    for (int i = 0; i < 4; ++i) {
      GLOAD_LDS16(gA + kk * 2048 + i * 32768, sA + i * 4096 + w * 1024);
      GLOAD_LDS16(gB + kk * 2048 + i * 32768, sB + i * 4096 + w * 1024);
    }
    __syncthreads();

    i32x8 af[4], bf[4];
    #pragma unroll
    for (int m = 0; m < 4; ++m) {
      const int gg = wm * 4 + m;
      i32x4 lo = *(const i32x4*)&sA[gg * 2048 + rl * 64 + kq * 16];
      i32x4 hi = *(const i32x4*)&sA[gg * 2048 + 1024 + rl * 64 + kq * 16];
      af[m] = (i32x8){lo[0], lo[1], lo[2], lo[3], hi[0], hi[1], hi[2], hi[3]};
    }
    #pragma unroll
    for (int n = 0; n < 4; ++n) {
      const int gg = wn * 4 + n;
      i32x4 lo = *(const i32x4*)&sB[gg * 2048 + rl * 64 + kq * 16];
      i32x4 hi = *(const i32x4*)&sB[gg * 2048 + 1024 + rl * 64 + kq * 16];
      bf[n] = (i32x8){lo[0], lo[1], lo[2], lo[3], hi[0], hi[1], hi[2], hi[3]};
    }
    #pragma unroll
    for (int m = 0; m < 4; ++m)
      #pragma unroll
      for (int n = 0; n < 4; ++n)
        acc[m][n] = __builtin_amdgcn_mfma_scale_f32_16x16x128_f8f6f4(
            af[m], bf[n], acc[m][n], 0, 0, 0, SCALE_A, 0, SCALE_B);
  }

  // fused epilogue (layout verified in round 1)
  #pragma unroll
  for (int n = 0; n < 4; ++n) {
    const int col = n0 + wn * 64 + n * 16 + rl;
    const int sv = sid[col];
    const float sbv = bias[sv] - __logf(sfreq[col]);
    #pragma unroll
    for (int m = 0; m < 4; ++m) {
      const int rbase = m0 + wm * 64 + m * 16 + kq * 4;
      #pragma unroll
      for (int i = 0; i < 4; ++i) {
        const int r = rbase + i;
        float c = acc[m][n][i] + sbv;
        if (tgt[r] == sv) c = NEG_INF_F;
        out[(size_t)r * LCOLS + 1 + col] = c;
      }
    }
  }
}

// ---------------- bf16 fallback (round-1 verified), no workspace ----------------
__device__ __forceinline__ void pack8(unsigned short* p, float4 a, float4 b) {
  u16x8 v;
  v[0] = f2bf(a.x); v[1] = f2bf(a.y); v[2] = f2bf(a.z); v[3] = f2bf(a.w);
  v[4] = f2bf(b.x); v[5] = f2bf(b.y); v[6] = f2bf(b.z); v[7] = f2bf(b.w);
  *(u16x8*)p = v;
}

__global__ __launch_bounds__(256)
void k_gemm_fb(const float* __restrict__ Af, const float* __restrict__ W,
               const int* __restrict__ tgt, const int* __restrict__ sid,
               const float* __restrict__ bias, const float* __restrict__ sfreq,
               float* __restrict__ out) {
  __shared__ unsigned short sA[128 * 32];
  __shared__ unsigned short sB[128 * 32];
  const int t = threadIdx.x;
  const int w = t >> 6, l = t & 63;
  const int m0 = blockIdx.y * 128, n0 = blockIdx.x * 128;
  const int wm = w >> 1, wn = w & 1;
  f32x4 acc[4][4] = {};
  const int srow = w * 16 + (l >> 2);
  const int scol = (l & 3) * 8;

  const int id0 = sid[n0 + srow], id1 = sid[n0 + 64 + srow];
  const float* gaf0 = Af + (size_t)(m0 + srow) * HID + scol;
  const float* gaf1 = gaf0 + (size_t)64 * HID;
  const float* gbf0 = W + (size_t)id0 * HID + scol;
  const float* gbf1 = W + (size_t)id1 * HID + scol;
  for (int kk = 0; kk < HID; kk += 32) {
    float4 a0 = *(const float4*)(gaf0 + kk), a1 = *(const float4*)(gaf0 + kk + 4);
    float4 a2 = *(const float4*)(gaf1 + kk), a3 = *(const float4*)(gaf1 + kk + 4);
    float4 b0 = *(const float4*)(gbf0 + kk), b1 = *(const float4*)(gbf0 + kk + 4);
    float4 b2 = *(const float4*)(gbf1 + kk), b3 = *(const float4*)(gbf1 + kk + 4);
    __syncthreads();
    pack8(&sA[t * 8], a0, a1);
    pack8(&sA[2048 + t * 8], a2, a3);
    pack8(&sB[t * 8], b0, b1);
    pack8(&sB[2048 + t * 8], b2, b3);
    __syncthreads();
    bf16x8 af_[4], bf_[4];
    const int rl_ = l & 15, kq_ = l >> 4;
    #pragma unroll
    for (int m = 0; m < 4; m++)
      af_[m] = *(const bf16x8*)&sA[(wm * 64 + m * 16 + rl_) * 32 + kq_ * 8];
    #pragma unroll
    for (int n = 0; n < 4; n++)
      bf_[n] = *(const bf16x8*)&sB[(wn * 64 + n * 16 + rl_) * 32 + kq_ * 8];
    #pragma unroll
    for (int m = 0; m < 4; m++)
      #pragma unroll
      for (int n = 0; n < 4; n++)
        acc[m][n] = __builtin_amdgcn_mfma_f32_16x16x32_bf16(af_[m], bf_[n],
                                                            acc[m][n], 0, 0, 0);
  }
  const int rl = l & 15, rq = l >> 4;
  #pragma unroll
  for (int n = 0; n < 4; ++n) {
    const int col = n0 + wn * 64 + n * 16 + rl;
    const int sv = sid[col];
    const float sbv = bias[sv] - __logf(sfreq[col]);
    #pragma unroll
    for (int m = 0; m < 4; ++m) {
      const int rbase = m0 + wm * 64 + m * 16 + rq * 4;
      #pragma unroll
      for (int i = 0; i < 4; ++i) {
        const int r = rbase + i;
        float c = acc[m][n][i] + sbv;
        if (tgt[r] == sv) c = NEG_INF_F;
        out[(size_t)r * LCOLS + 1 + col] = c;
      }
    }
  }
}

extern "C" void kernel_launch(void* const* d_in, const int* in_sizes, int n_in,
                              void* d_out, int out_size, void* d_ws, size_t ws_size,
                              hipStream_t stream) {
  (void)in_sizes; (void)n_in; (void)out_size;
  const float* output      = (const float*)d_in[0];
  const int*   targets     = (const int*)d_in[1];
  const int*   sample_ids  = (const int*)d_in[2];
  const float* true_freq   = (const float*)d_in[3];
  const float* sample_freq = (const float*)d_in[4];
  const float* weight      = (const float*)d_in[5];
  const float* bias        = (const float*)d_in[6];
  float* out = (float*)d_out;

  const size_t needA = (size_t)NROWS * HID;   // 8 MB fp8
  const size_t needB = (size_t)NSAMP * HID;   // 8 MB fp8
  const bool use_ws = ws_size >= (needA + needB);

  k_true<<<NROWS / 4, 256, 0, stream>>>(output, targets, weight, bias, true_freq, out);

  dim3 grid(NSAMP / 128, NROWS / 128);
  if (use_ws) {
    unsigned char* Ab = (unsigned char*)d_ws;
    unsigned char* Bb = Ab + needA;
    k_cvtA<<<2048, 256, 0, stream>>>(output, Ab);
    k_gatherB<<<2048, 256, 0, stream>>>(weight, sample_ids, Bb);
    k_gemm8<<<grid, 256, 0, stream>>>(Ab, Bb, targets, sample_ids, bias,
                                      sample_freq, out);
  } else {
    k_gemm_fb<<<grid, 256, 0, stream>>>(output, weight, targets, sample_ids,
                                        bias, sample_freq, out);
  }
}

// Round 3
// 237.363 us; speedup vs baseline: 1.1470x; 1.0074x over previous
//
#include <hip/hip_runtime.h>

#define NROWS 8192
#define HID   1024
#define NSAMP 8192
#define LCOLS 8193          // NSAMP + 1
#define NEG_INF_F (-1e37f)

#define SCALE_A 127         // E8M0: 2^0
#define SCALE_B 122         // E8M0: 2^-5  (W rows pre-scaled by 32)

typedef __attribute__((ext_vector_type(4))) int   i32x4;
typedef __attribute__((ext_vector_type(8))) int   i32x8;
typedef __attribute__((ext_vector_type(4))) float f32x4;
typedef __attribute__((ext_vector_type(8))) __bf16 bf16x8;
typedef __attribute__((ext_vector_type(8))) unsigned short u16x8;

__device__ __forceinline__ unsigned short f2bf(float x) {
  unsigned u = __float_as_uint(x);
  u += 0x7fffu + ((u >> 16) & 1u);
  return (unsigned short)(u >> 16);
}

#define GLOAD_LDS16(g, l)                                                      \
  __builtin_amdgcn_global_load_lds(                                            \
      (const __attribute__((address_space(1))) void*)(g),                      \
      (__attribute__((address_space(3))) void*)(l), 16, 0, 0)

// ===================== fp8 tiled-workspace layout (v2: lane-linear) ==========
// Element (row = G*16 + rl, k = kk*128 + kq*32 + h*16 + j), rl<16, kq<4, h<2,
// j<16 lives at:
//   off = (G*8 + kk)*2048 + h*1024 + kq*256 + rl*16 + j
// MFMA fragment lane l (rl=l&15, kq=l>>4) reads 16B at
//   gg*2048 + h*1024 + kq*256 + rl*16  ==  gg*2048 + h*1024 + l*16
// -> ds_read_b128 address is EXACTLY lane*16: each 8-lane phase covers all
//    32 banks once. Zero conflicts (round-2's rl*64+kq*16 was 8-way).
// global_load_lds staging stays fully linear (unchanged from round 2).
// The induced k-permutation is identical for A and B -> dot products unchanged.

__device__ __forceinline__ int pk4(float a, float b, float c, float d) {
  int r = __builtin_amdgcn_cvt_pk_fp8_f32(a, b, 0, 0);
  r = __builtin_amdgcn_cvt_pk_fp8_f32(c, d, r, 1);
  return r;
}

// one thread per 16 output bytes; total 8 MB / 16 = 524288 threads
__global__ void k_cvtA(const float* __restrict__ A, unsigned char* __restrict__ Ab) {
  const int t = blockIdx.x * blockDim.x + threadIdx.x;
  const int rl = t & 15, kq = (t >> 4) & 3, h = (t >> 6) & 1;
  const int kk = (t >> 7) & 7, G = t >> 10;
  const int row = G * 16 + rl;
  const int k0 = kk * 128 + kq * 32 + h * 16;
  const float4* s = (const float4*)(A + (size_t)row * HID + k0);
  float4 f0 = s[0], f1 = s[1], f2 = s[2], f3 = s[3];
  int4 o;
  o.x = pk4(f0.x, f0.y, f0.z, f0.w);
  o.y = pk4(f1.x, f1.y, f1.z, f1.w);
  o.z = pk4(f2.x, f2.y, f2.z, f2.w);
  o.w = pk4(f3.x, f3.y, f3.z, f3.w);
  ((int4*)Ab)[t] = o;
}

__global__ void k_gatherB(const float* __restrict__ W, const int* __restrict__ sid,
                          unsigned char* __restrict__ Bb) {
  const int t = blockIdx.x * blockDim.x + threadIdx.x;
  const int rl = t & 15, kq = (t >> 4) & 3, h = (t >> 6) & 1;
  const int kk = (t >> 7) & 7, G = t >> 10;
  const int srow = G * 16 + rl;
  const int id = sid[srow];
  const int k0 = kk * 128 + kq * 32 + h * 16;
  const float4* s = (const float4*)(W + (size_t)id * HID + k0);
  float4 f0 = s[0], f1 = s[1], f2 = s[2], f3 = s[3];
  const float m = 32.0f;   // descaled in-HW by SCALE_B = 2^-5
  int4 o;
  o.x = pk4(f0.x * m, f0.y * m, f0.z * m, f0.w * m);
  o.y = pk4(f1.x * m, f1.y * m, f1.z * m, f1.w * m);
  o.z = pk4(f2.x * m, f2.y * m, f2.z * m, f2.w * m);
  o.w = pk4(f3.x * m, f3.y * m, f3.z * m, f3.w * m);
  ((int4*)Bb)[t] = o;
}

// ------------- true-class logits (column 0) + new_targets ----------------
__global__ void k_true(const float* __restrict__ X, const int* __restrict__ tgt,
                       const float* __restrict__ W, const float* __restrict__ bias,
                       const float* __restrict__ tfreq, float* __restrict__ out) {
  const int n = blockIdx.x * 4 + (threadIdx.x >> 6);
  const int l = threadIdx.x & 63;
  const int tg = tgt[n];
  float4 a = ((const float4*)(X + (size_t)n * HID))[l];
  float4 wv = ((const float4*)(W + (size_t)tg * HID))[l];
  float p = a.x * wv.x + a.y * wv.y + a.z * wv.z + a.w * wv.w;
  #pragma unroll
  for (int off = 32; off > 0; off >>= 1) p += __shfl_down(p, off);
  if (l == 0) {
    out[(size_t)n * LCOLS] = p + bias[tg] - __logf(tfreq[n]);
    ((int*)out)[(size_t)NROWS * LCOLS + n] = 0;
  }
}

// ---------------- 128x128 MX-fp8 NT-GEMM with fused epilogue ----------------
__global__ __launch_bounds__(256)
void k_gemm8(const unsigned char* __restrict__ Ab, const unsigned char* __restrict__ Bb,
             const int* __restrict__ tgt, const int* __restrict__ sid,
             const float* __restrict__ bias, const float* __restrict__ sfreq,
             float* __restrict__ out) {
  __shared__ unsigned char sA[16384];
  __shared__ unsigned char sB[16384];
  const int t = threadIdx.x, w = t >> 6, l = t & 63;
  int bid = blockIdx.y * 64 + blockIdx.x;
  bid = (bid & 7) * 512 + (bid >> 3);            // XCD swizzle (4096 % 8 == 0)
  const int m0 = (bid >> 6) * 128, n0 = (bid & 63) * 128;
  const int wm = w >> 1, wn = w & 1;
  const int rl = l & 15, kq = l >> 4;
  f32x4 acc[4][4] = {};

  // staging: issue i covers gg = 2i + (w>>1), h = w&1; 1 KiB per wave-issue
  const unsigned char* gA = Ab + (size_t)m0 * 1024 + (size_t)(w >> 1) * 16384 +
                            (w & 1) * 1024 + l * 16;
  const unsigned char* gB = Bb + (size_t)n0 * 1024 + (size_t)(w >> 1) * 16384 +
                            (w & 1) * 1024 + l * 16;

  for (int kk = 0; kk < 8; ++kk) {
    __syncthreads();
    #pragma unroll
    for (int i = 0; i < 4; ++i) {
      GLOAD_LDS16(gA + kk * 2048 + i * 32768, sA + i * 4096 + w * 1024);
      GLOAD_LDS16(gB + kk * 2048 + i * 32768, sB + i * 4096 + w * 1024);
    }
    __syncthreads();

    i32x8 af[4], bf[4];
    #pragma unroll
    for (int m = 0; m < 4; ++m) {
      const int gg = wm * 4 + m;
      i32x4 lo = *(const i32x4*)&sA[gg * 2048 + l * 16];
      i32x4 hi = *(const i32x4*)&sA[gg * 2048 + 1024 + l * 16];
      af[m] = (i32x8){lo[0], lo[1], lo[2], lo[3], hi[0], hi[1], hi[2], hi[3]};
    }
    #pragma unroll
    for (int n = 0; n < 4; ++n) {
      const int gg = wn * 4 + n;
      i32x4 lo = *(const i32x4*)&sB[gg * 2048 + l * 16];
      i32x4 hi = *(const i32x4*)&sB[gg * 2048 + 1024 + l * 16];
      bf[n] = (i32x8){lo[0], lo[1], lo[2], lo[3], hi[0], hi[1], hi[2], hi[3]};
    }
    #pragma unroll
    for (int m = 0; m < 4; ++m)
      #pragma unroll
      for (int n = 0; n < 4; ++n)
        acc[m][n] = __builtin_amdgcn_mfma_scale_f32_16x16x128_f8f6f4(
            af[m], bf[n], acc[m][n], 0, 0, 0, SCALE_A, 0, SCALE_B);
  }

  // fused epilogue (layout verified rounds 1-2)
  #pragma unroll
  for (int n = 0; n < 4; ++n) {
    const int col = n0 + wn * 64 + n * 16 + rl;
    const int sv = sid[col];
    const float sbv = bias[sv] - __logf(sfreq[col]);
    #pragma unroll
    for (int m = 0; m < 4; ++m) {
      const int rbase = m0 + wm * 64 + m * 16 + kq * 4;
      #pragma unroll
      for (int i = 0; i < 4; ++i) {
        const int r = rbase + i;
        float c = acc[m][n][i] + sbv;
        if (tgt[r] == sv) c = NEG_INF_F;
        out[(size_t)r * LCOLS + 1 + col] = c;
      }
    }
  }
}

// ---------------- bf16 fallback (round-1 verified), no workspace ----------------
__device__ __forceinline__ void pack8(unsigned short* p, float4 a, float4 b) {
  u16x8 v;
  v[0] = f2bf(a.x); v[1] = f2bf(a.y); v[2] = f2bf(a.z); v[3] = f2bf(a.w);
  v[4] = f2bf(b.x); v[5] = f2bf(b.y); v[6] = f2bf(b.z); v[7] = f2bf(b.w);
  *(u16x8*)p = v;
}

__global__ __launch_bounds__(256)
void k_gemm_fb(const float* __restrict__ Af, const float* __restrict__ W,
               const int* __restrict__ tgt, const int* __restrict__ sid,
               const float* __restrict__ bias, const float* __restrict__ sfreq,
               float* __restrict__ out) {
  __shared__ unsigned short sA[128 * 32];
  __shared__ unsigned short sB[128 * 32];
  const int t = threadIdx.x;
  const int w = t >> 6, l = t & 63;
  const int m0 = blockIdx.y * 128, n0 = blockIdx.x * 128;
  const int wm = w >> 1, wn = w & 1;
  f32x4 acc[4][4] = {};
  const int srow = w * 16 + (l >> 2);
  const int scol = (l & 3) * 8;

  const int id0 = sid[n0 + srow], id1 = sid[n0 + 64 + srow];
  const float* gaf0 = Af + (size_t)(m0 + srow) * HID + scol;
  const float* gaf1 = gaf0 + (size_t)64 * HID;
  const float* gbf0 = W + (size_t)id0 * HID + scol;
  const float* gbf1 = W + (size_t)id1 * HID + scol;
  for (int kk = 0; kk < HID; kk += 32) {
    float4 a0 = *(const float4*)(gaf0 + kk), a1 = *(const float4*)(gaf0 + kk + 4);
    float4 a2 = *(const float4*)(gaf1 + kk), a3 = *(const float4*)(gaf1 + kk + 4);
    float4 b0 = *(const float4*)(gbf0 + kk), b1 = *(const float4*)(gbf0 + kk + 4);
    float4 b2 = *(const float4*)(gbf1 + kk), b3 = *(const float4*)(gbf1 + kk + 4);
    __syncthreads();
    pack8(&sA[t * 8], a0, a1);
    pack8(&sA[2048 + t * 8], a2, a3);
    pack8(&sB[t * 8], b0, b1);
    pack8(&sB[2048 + t * 8], b2, b3);
    __syncthreads();
    bf16x8 af_[4], bf_[4];
    const int rl_ = l & 15, kq_ = l >> 4;
    #pragma unroll
    for (int m = 0; m < 4; m++)
      af_[m] = *(const bf16x8*)&sA[(wm * 64 + m * 16 + rl_) * 32 + kq_ * 8];
    #pragma unroll
    for (int n = 0; n < 4; n++)
      bf_[n] = *(const bf16x8*)&sB[(wn * 64 + n * 16 + rl_) * 32 + kq_ * 8];
    #pragma unroll
    for (int m = 0; m < 4; m++)
      #pragma unroll
      for (int n = 0; n < 4; n++)
        acc[m][n] = __builtin_amdgcn_mfma_f32_16x16x32_bf16(af_[m], bf_[n],
                                                            acc[m][n], 0, 0, 0);
  }
  const int rl = l & 15, rq = l >> 4;
  #pragma unroll
  for (int n = 0; n < 4; ++n) {
    const int col = n0 + wn * 64 + n * 16 + rl;
    const int sv = sid[col];
    const float sbv = bias[sv] - __logf(sfreq[col]);
    #pragma unroll
    for (int m = 0; m < 4; ++m) {
      const int rbase = m0 + wm * 64 + m * 16 + rq * 4;
      #pragma unroll
      for (int i = 0; i < 4; ++i) {
        const int r = rbase + i;
        float c = acc[m][n][i] + sbv;
        if (tgt[r] == sv) c = NEG_INF_F;
        out[(size_t)r * LCOLS + 1 + col] = c;
      }
    }
  }
}

extern "C" void kernel_launch(void* const* d_in, const int* in_sizes, int n_in,
                              void* d_out, int out_size, void* d_ws, size_t ws_size,
                              hipStream_t stream) {
  (void)in_sizes; (void)n_in; (void)out_size;
  const float* output      = (const float*)d_in[0];
  const int*   targets     = (const int*)d_in[1];
  const int*   sample_ids  = (const int*)d_in[2];
  const float* true_freq   = (const float*)d_in[3];
  const float* sample_freq = (const float*)d_in[4];
  const float* weight      = (const float*)d_in[5];
  const float* bias        = (const float*)d_in[6];
  float* out = (float*)d_out;

  const size_t needA = (size_t)NROWS * HID;   // 8 MB fp8
  const size_t needB = (size_t)NSAMP * HID;   // 8 MB fp8
  const bool use_ws = ws_size >= (needA + needB);

  k_true<<<NROWS / 4, 256, 0, stream>>>(output, targets, weight, bias, true_freq, out);

  dim3 grid(NSAMP / 128, NROWS / 128);
  if (use_ws) {
    unsigned char* Ab = (unsigned char*)d_ws;
    unsigned char* Bb = Ab + needA;
    k_cvtA<<<2048, 256, 0, stream>>>(output, Ab);
    k_gatherB<<<2048, 256, 0, stream>>>(weight, sample_ids, Bb);
    k_gemm8<<<grid, 256, 0, stream>>>(Ab, Bb, targets, sample_ids, bias,
                                      sample_freq, out);
  } else {
    k_gemm_fb<<<grid, 256, 0, stream>>>(output, weight, targets, sample_ids,
                                        bias, sample_freq, out);
  }
}

// Round 4
// 196.271 us; speedup vs baseline: 1.3871x; 1.2094x over previous
//
#include <hip/hip_runtime.h>

#define NROWS 8192
#define HID   1024
#define NSAMP 8192
#define LCOLS 8193          // NSAMP + 1
#define NEG_INF_F (-1e37f)

#define SCALE_A 127         // E8M0: 2^0
#define SCALE_B 122         // E8M0: 2^-5  (W rows pre-scaled by 32)

typedef __attribute__((ext_vector_type(4))) int   i32x4;
typedef __attribute__((ext_vector_type(8))) int   i32x8;
typedef __attribute__((ext_vector_type(4))) float f32x4;
typedef f32x4 __attribute__((aligned(4))) f32x4u;   // 4B-aligned vector store
typedef __attribute__((ext_vector_type(8))) __bf16 bf16x8;
typedef __attribute__((ext_vector_type(8))) unsigned short u16x8;

__device__ __forceinline__ unsigned short f2bf(float x) {
  unsigned u = __float_as_uint(x);
  u += 0x7fffu + ((u >> 16) & 1u);
  return (unsigned short)(u >> 16);
}

#define GLOAD_LDS16(g, l)                                                      \
  __builtin_amdgcn_global_load_lds(                                            \
      (const __attribute__((address_space(1))) void*)(g),                      \
      (__attribute__((address_space(3))) void*)(l), 16, 0, 0)

// ===================== fp8 tiled-workspace layout (lane-linear, verified r3) ==
// Element (row = G*16 + rl, k = kk*128 + kq*32 + h*16 + j) lives at:
//   off = (G*8 + kk)*2048 + h*1024 + kq*256 + rl*16 + j
// ds_read_b128 address == lane*16 -> zero bank conflicts (verified: r3 PMC 0).
// Same k-permutation for A and B -> dot products unchanged.

__device__ __forceinline__ int pk4(float a, float b, float c, float d) {
  int r = __builtin_amdgcn_cvt_pk_fp8_f32(a, b, 0, 0);
  r = __builtin_amdgcn_cvt_pk_fp8_f32(c, d, r, 1);
  return r;
}

__global__ void k_cvtA(const float* __restrict__ A, unsigned char* __restrict__ Ab) {
  const int t = blockIdx.x * blockDim.x + threadIdx.x;
  const int rl = t & 15, kq = (t >> 4) & 3, h = (t >> 6) & 1;
  const int kk = (t >> 7) & 7, G = t >> 10;
  const int row = G * 16 + rl;
  const int k0 = kk * 128 + kq * 32 + h * 16;
  const float4* s = (const float4*)(A + (size_t)row * HID + k0);
  float4 f0 = s[0], f1 = s[1], f2 = s[2], f3 = s[3];
  int4 o;
  o.x = pk4(f0.x, f0.y, f0.z, f0.w);
  o.y = pk4(f1.x, f1.y, f1.z, f1.w);
  o.z = pk4(f2.x, f2.y, f2.z, f2.w);
  o.w = pk4(f3.x, f3.y, f3.z, f3.w);
  ((int4*)Ab)[t] = o;
}

__global__ void k_gatherB(const float* __restrict__ W, const int* __restrict__ sid,
                          unsigned char* __restrict__ Bb) {
  const int t = blockIdx.x * blockDim.x + threadIdx.x;
  const int rl = t & 15, kq = (t >> 4) & 3, h = (t >> 6) & 1;
  const int kk = (t >> 7) & 7, G = t >> 10;
  const int srow = G * 16 + rl;
  const int id = sid[srow];
  const int k0 = kk * 128 + kq * 32 + h * 16;
  const float4* s = (const float4*)(W + (size_t)id * HID + k0);
  float4 f0 = s[0], f1 = s[1], f2 = s[2], f3 = s[3];
  const float m = 32.0f;   // descaled in-HW by SCALE_B = 2^-5
  int4 o;
  o.x = pk4(f0.x * m, f0.y * m, f0.z * m, f0.w * m);
  o.y = pk4(f1.x * m, f1.y * m, f1.z * m, f1.w * m);
  o.z = pk4(f2.x * m, f2.y * m, f2.z * m, f2.w * m);
  o.w = pk4(f3.x * m, f3.y * m, f3.z * m, f3.w * m);
  ((int4*)Bb)[t] = o;
}

// ------------- true-class logits (column 0) + new_targets ----------------
__global__ void k_true(const float* __restrict__ X, const int* __restrict__ tgt,
                       const float* __restrict__ W, const float* __restrict__ bias,
                       const float* __restrict__ tfreq, float* __restrict__ out) {
  const int n = blockIdx.x * 4 + (threadIdx.x >> 6);
  const int l = threadIdx.x & 63;
  const int tg = tgt[n];
  float4 a = ((const float4*)(X + (size_t)n * HID))[l];
  float4 wv = ((const float4*)(W + (size_t)tg * HID))[l];
  float p = a.x * wv.x + a.y * wv.y + a.z * wv.z + a.w * wv.w;
  #pragma unroll
  for (int off = 32; off > 0; off >>= 1) p += __shfl_down(p, off);
  if (l == 0) {
    out[(size_t)n * LCOLS] = p + bias[tg] - __logf(tfreq[n]);
    ((int*)out)[(size_t)NROWS * LCOLS + n] = 0;
  }
}

// ------- 128x128 MX-fp8 NT-GEMM, 2-phase pipelined, LDS-restaged stores ------
__global__ __launch_bounds__(256)
void k_gemm8(const unsigned char* __restrict__ Ab, const unsigned char* __restrict__ Bb,
             const int* __restrict__ tgt, const int* __restrict__ sid,
             const float* __restrict__ bias, const float* __restrict__ sfreq,
             float* __restrict__ out) {
  __shared__ unsigned char lds[65536];   // dbuf: [buf*32768] A(16K)+B(16K); epilogue: 128x128 f32
  const int t = threadIdx.x, w = t >> 6, l = t & 63;
  int bid = blockIdx.y * 64 + blockIdx.x;
  bid = (bid & 7) * 512 + (bid >> 3);            // XCD swizzle (4096 % 8 == 0)
  const int m0 = (bid >> 6) * 128, n0 = (bid & 63) * 128;
  const int wm = w >> 1, wn = w & 1;
  const int rl = l & 15, kq = l >> 4;
  f32x4 acc[4][4] = {};

  const unsigned char* gA = Ab + (size_t)m0 * 1024 + (size_t)(w >> 1) * 16384 +
                            (w & 1) * 1024 + l * 16;
  const unsigned char* gB = Bb + (size_t)n0 * 1024 + (size_t)(w >> 1) * 16384 +
                            (w & 1) * 1024 + l * 16;

#define STAGE(buf_, kk_)                                                       \
  do {                                                                         \
    unsigned char* _d = lds + (buf_) * 32768 + w * 1024;                       \
    const unsigned char* _ga = gA + (kk_) * 2048;                              \
    const unsigned char* _gb = gB + (kk_) * 2048;                              \
    _Pragma("unroll") for (int i_ = 0; i_ < 4; ++i_) {                         \
      GLOAD_LDS16(_ga + i_ * 32768, _d + i_ * 4096);                           \
      GLOAD_LDS16(_gb + i_ * 32768, _d + 16384 + i_ * 4096);                   \
    }                                                                          \
  } while (0)

  // prologue: stage tile 0, drain, barrier
  STAGE(0, 0);
  asm volatile("s_waitcnt vmcnt(0)" ::: "memory");
  __builtin_amdgcn_s_barrier();

  int buf = 0;
  for (int kk = 0; kk < 8; ++kk) {
    const unsigned char* sAb = lds + buf * 32768;
    const unsigned char* sBb = sAb + 16384;

    // 1) fragment ds_reads (from current buffer)
    i32x8 af[4], bf[4];
    #pragma unroll
    for (int m = 0; m < 4; ++m) {
      const int gg = wm * 4 + m;
      i32x4 lo = *(const i32x4*)&sAb[gg * 2048 + l * 16];
      i32x4 hi = *(const i32x4*)&sAb[gg * 2048 + 1024 + l * 16];
      af[m] = (i32x8){lo[0], lo[1], lo[2], lo[3], hi[0], hi[1], hi[2], hi[3]};
    }
    #pragma unroll
    for (int n = 0; n < 4; ++n) {
      const int gg = wn * 4 + n;
      i32x4 lo = *(const i32x4*)&sBb[gg * 2048 + l * 16];
      i32x4 hi = *(const i32x4*)&sBb[gg * 2048 + 1024 + l * 16];
      bf[n] = (i32x8){lo[0], lo[1], lo[2], lo[3], hi[0], hi[1], hi[2], hi[3]};
    }
    __builtin_amdgcn_sched_barrier(0);

    // 2) prefetch next tile into the other buffer (latency hides under MFMA)
    if (kk < 7) STAGE(buf ^ 1, kk + 1);
    __builtin_amdgcn_sched_barrier(0);

    // 3) MFMA cluster
    __builtin_amdgcn_s_setprio(1);
    #pragma unroll
    for (int m = 0; m < 4; ++m)
      #pragma unroll
      for (int n = 0; n < 4; ++n)
        acc[m][n] = __builtin_amdgcn_mfma_scale_f32_16x16x128_f8f6f4(
            af[m], bf[n], acc[m][n], 0, 0, 0, SCALE_A, 0, SCALE_B);
    __builtin_amdgcn_s_setprio(0);

    // 4) single drain + barrier per tile
    asm volatile("s_waitcnt vmcnt(0)" ::: "memory");
    __builtin_amdgcn_s_barrier();
    buf ^= 1;
  }
#undef STAGE

  // ---- epilogue: restage tile in LDS, store 512B-contiguous row segments ----
  float* tile = (float*)lds;   // 128 rows x 128 cols f32 = 64 KB
  #pragma unroll
  for (int n = 0; n < 4; ++n) {
    const int col = wn * 64 + n * 16 + rl;         // local col
    const int gcol = n0 + col;
    const int sv = sid[gcol];
    const float sbv = bias[sv] - __logf(sfreq[gcol]);
    #pragma unroll
    for (int m = 0; m < 4; ++m) {
      const int rb = wm * 64 + m * 16 + kq * 4;    // local row base
      #pragma unroll
      for (int i = 0; i < 4; ++i) {
        const int r = rb + i;
        float c = acc[m][n][i] + sbv;
        if (tgt[m0 + r] == sv) c = NEG_INF_F;
        tile[r * 128 + (col ^ ((r & 4) << 2))] = c;   // 2-way banks: free
      }
    }
  }
  __syncthreads();
  #pragma unroll
  for (int p = 0; p < 16; ++p) {
    const int idx = p * 256 + t;
    const int r = idx >> 5;                        // local row
    const int c16 = idx & 31;                      // 16B unit within row
    f32x4 v = *(const f32x4*)&tile[r * 128 + ((c16 * 4) ^ ((r & 4) << 2))];
    *(f32x4u*)&out[(size_t)(m0 + r) * LCOLS + 1 + n0 + c16 * 4] = v;
  }
}

// ---------------- bf16 fallback (round-1 verified), no workspace ----------------
__device__ __forceinline__ void pack8(unsigned short* p, float4 a, float4 b) {
  u16x8 v;
  v[0] = f2bf(a.x); v[1] = f2bf(a.y); v[2] = f2bf(a.z); v[3] = f2bf(a.w);
  v[4] = f2bf(b.x); v[5] = f2bf(b.y); v[6] = f2bf(b.z); v[7] = f2bf(b.w);
  *(u16x8*)p = v;
}

__global__ __launch_bounds__(256)
void k_gemm_fb(const float* __restrict__ Af, const float* __restrict__ W,
               const int* __restrict__ tgt, const int* __restrict__ sid,
               const float* __restrict__ bias, const float* __restrict__ sfreq,
               float* __restrict__ out) {
  __shared__ unsigned short sA[128 * 32];
  __shared__ unsigned short sB[128 * 32];
  const int t = threadIdx.x;
  const int w = t >> 6, l = t & 63;
  const int m0 = blockIdx.y * 128, n0 = blockIdx.x * 128;
  const int wm = w >> 1, wn = w & 1;
  f32x4 acc[4][4] = {};
  const int srow = w * 16 + (l >> 2);
  const int scol = (l & 3) * 8;

  const int id0 = sid[n0 + srow], id1 = sid[n0 + 64 + srow];
  const float* gaf0 = Af + (size_t)(m0 + srow) * HID + scol;
  const float* gaf1 = gaf0 + (size_t)64 * HID;
  const float* gbf0 = W + (size_t)id0 * HID + scol;
  const float* gbf1 = W + (size_t)id1 * HID + scol;
  for (int kk = 0; kk < HID; kk += 32) {
    float4 a0 = *(const float4*)(gaf0 + kk), a1 = *(const float4*)(gaf0 + kk + 4);
    float4 a2 = *(const float4*)(gaf1 + kk), a3 = *(const float4*)(gaf1 + kk + 4);
    float4 b0 = *(const float4*)(gbf0 + kk), b1 = *(const float4*)(gbf0 + kk + 4);
    float4 b2 = *(const float4*)(gbf1 + kk), b3 = *(const float4*)(gbf1 + kk + 4);
    __syncthreads();
    pack8(&sA[t * 8], a0, a1);
    pack8(&sA[2048 + t * 8], a2, a3);
    pack8(&sB[t * 8], b0, b1);
    pack8(&sB[2048 + t * 8], b2, b3);
    __syncthreads();
    bf16x8 af_[4], bf_[4];
    const int rl_ = l & 15, kq_ = l >> 4;
    #pragma unroll
    for (int m = 0; m < 4; m++)
      af_[m] = *(const bf16x8*)&sA[(wm * 64 + m * 16 + rl_) * 32 + kq_ * 8];
    #pragma unroll
    for (int n = 0; n < 4; n++)
      bf_[n] = *(const bf16x8*)&sB[(wn * 64 + n * 16 + rl_) * 32 + kq_ * 8];
    #pragma unroll
    for (int m = 0; m < 4; m++)
      #pragma unroll
      for (int n = 0; n < 4; n++)
        acc[m][n] = __builtin_amdgcn_mfma_f32_16x16x32_bf16(af_[m], bf_[n],
                                                            acc[m][n], 0, 0, 0);
  }
  const int rl = l & 15, rq = l >> 4;
  #pragma unroll
  for (int n = 0; n < 4; ++n) {
    const int col = n0 + wn * 64 + n * 16 + rl;
    const int sv = sid[col];
    const float sbv = bias[sv] - __logf(sfreq[col]);
    #pragma unroll
    for (int m = 0; m < 4; ++m) {
      const int rbase = m0 + wm * 64 + m * 16 + rq * 4;
      #pragma unroll
      for (int i = 0; i < 4; ++i) {
        const int r = rbase + i;
        float c = acc[m][n][i] + sbv;
        if (tgt[r] == sv) c = NEG_INF_F;
        out[(size_t)r * LCOLS + 1 + col] = c;
      }
    }
  }
}

extern "C" void kernel_launch(void* const* d_in, const int* in_sizes, int n_in,
                              void* d_out, int out_size, void* d_ws, size_t ws_size,
                              hipStream_t stream) {
  (void)in_sizes; (void)n_in; (void)out_size;
  const float* output      = (const float*)d_in[0];
  const int*   targets     = (const int*)d_in[1];
  const int*   sample_ids  = (const int*)d_in[2];
  const float* true_freq   = (const float*)d_in[3];
  const float* sample_freq = (const float*)d_in[4];
  const float* weight      = (const float*)d_in[5];
  const float* bias        = (const float*)d_in[6];
  float* out = (float*)d_out;

  const size_t needA = (size_t)NROWS * HID;   // 8 MB fp8
  const size_t needB = (size_t)NSAMP * HID;   // 8 MB fp8
  const bool use_ws = ws_size >= (needA + needB);

  k_true<<<NROWS / 4, 256, 0, stream>>>(output, targets, weight, bias, true_freq, out);

  dim3 grid(NSAMP / 128, NROWS / 128);
  if (use_ws) {
    unsigned char* Ab = (unsigned char*)d_ws;
    unsigned char* Bb = Ab + needA;
    k_cvtA<<<2048, 256, 0, stream>>>(output, Ab);
    k_gatherB<<<2048, 256, 0, stream>>>(weight, sample_ids, Bb);
    k_gemm8<<<grid, 256, 0, stream>>>(Ab, Bb, targets, sample_ids, bias,
                                      sample_freq, out);
  } else {
    k_gemm_fb<<<grid, 256, 0, stream>>>(output, weight, targets, sample_ids,
                                        bias, sample_freq, out);
  }
}